// Round 13
// baseline (164.208 us; speedup 1.0000x reference)
//
#include <hip/hip_runtime.h>

#define V 50000
#define E_DIM 256
#define H_DIM 512
#define H2 1024
#define G3 1536
#define BSZ 64
#define SEQ 200
#define KX 1280
#define MROWS 12800
#define NBLK_WO 782  // ceil(50000/64)

// ws offsets (float units)
#define XBF_OFF   0        // 64*1280 bf16
#define H0_OFF    40960    // 64*512 f32
#define H0BF_OFF  73728    // 64*512 bf16
#define GI_OFF    90112    // 64*1536 f32
#define GH_OFF    188416   // 64*1536 f32
#define STBF_OFF  286720   // 64*512 bf16
#define WCBF_OFF  303104   // 512*1024 bf16
#define SC_OFF    565248   // 4*12800 f32 (n-tile partials)
#define REDG_OFF  616448   // 64*782*2 f32
#define RED_OFF   716544   // 64*2 f32
#define ENCBF_OFF 716672   // 12800*1024 bf16 = 3276800 f

// d_out layout (floats)
#define OUT_STATE 3200000
#define OUT_W     3232768

typedef __attribute__((ext_vector_type(8))) short bf16x8;
typedef __attribute__((ext_vector_type(4))) float f32x4;

__device__ __forceinline__ float sigmf(float x) { return 1.f / (1.f + __expf(-x)); }

__device__ __forceinline__ ushort f2bf(float f) {
  uint u = __float_as_uint(f);
  uint r = (u + 0x7FFFu + ((u >> 16) & 1u)) >> 16;
  return (ushort)r;
}

__device__ __forceinline__ float tanhfast(float x) {
  float xc = fminf(15.f, fmaxf(-15.f, x));
  float e = __expf(2.f * xc);
  return (e - 1.f) * __builtin_amdgcn_rcpf(e + 1.f);
}

// packed f32->bf16 (RNE)
__device__ __forceinline__ bf16x8 cvt8(float4 a, float4 b) {
  union { bf16x8 v; uint u[4]; } r;
  asm("v_cvt_pk_bf16_f32 %0, %1, %2" : "=v"(r.u[0]) : "v"(a.x), "v"(a.y));
  asm("v_cvt_pk_bf16_f32 %0, %1, %2" : "=v"(r.u[1]) : "v"(a.z), "v"(a.w));
  asm("v_cvt_pk_bf16_f32 %0, %1, %2" : "=v"(r.u[2]) : "v"(b.x), "v"(b.y));
  asm("v_cvt_pk_bf16_f32 %0, %1, %2" : "=v"(r.u[3]) : "v"(b.z), "v"(b.w));
  return r.v;
}

// async global->LDS, 16B per lane; lds base wave-uniform, HW adds lane*16.
__device__ __forceinline__ void gload16(const void* g, void* l) {
  __builtin_amdgcn_global_load_lds(
      (__attribute__((address_space(1))) void*)(g),
      (__attribute__((address_space(3))) void*)(l), 16, 0, 0);
}

// ---------------- kprep: Wc f32->bf16 (0..511) | encoded f32->bf16 (512..3711) |
//                  x_bf/h0 build (3712..3775)
__global__ void kprep(const float* __restrict__ Wc_W, ushort* __restrict__ Wc_bf,
                      const float* __restrict__ encoded, ushort* __restrict__ enc_bf,
                      const int* __restrict__ input_idx,
                      const float* __restrict__ prev_state, const float* __restrict__ weighted,
                      const int* __restrict__ order_p, const float* __restrict__ embed_W,
                      const float* __restrict__ Ws_W, const float* __restrict__ Ws_b,
                      ushort* __restrict__ x_bf, float* __restrict__ h0,
                      ushort* __restrict__ h0_bf) {
  int bid = blockIdx.x, tid = threadIdx.x;
  if (bid < 512) {
    int i = bid * 256 + tid;
    float4 v = ((const float4*)Wc_W)[i];
    ushort4 o;
    o.x = f2bf(v.x); o.y = f2bf(v.y); o.z = f2bf(v.z); o.w = f2bf(v.w);
    ((ushort4*)Wc_bf)[i] = o;
    return;
  }
  if (bid < 3712) {
    int base = (bid - 512) * 1024;
#pragma unroll
    for (int j = 0; j < 4; ++j) {
      int i = base + j * 256 + tid;
      float4 v = ((const float4*)encoded)[i];
      ushort4 o;
      o.x = f2bf(v.x); o.y = f2bf(v.y); o.z = f2bf(v.z); o.w = f2bf(v.w);
      ((ushort4*)enc_bf)[i] = o;
    }
    return;
  }
  int b = bid - 3712;
  int order = order_p[0];
  int idx = input_idx[b];
  x_bf[b * KX + tid] = f2bf(embed_W[(size_t)idx * E_DIM + tid]);
  if (order != 0) {
    for (int j = tid; j < H2; j += 256) x_bf[b * KX + E_DIM + j] = f2bf(weighted[b * H2 + j]);
    for (int j = tid; j < H_DIM; j += 256) {
      float v = prev_state[b * H_DIM + j];
      h0[b * H_DIM + j] = v;
      h0_bf[b * H_DIM + j] = f2bf(v);
    }
  } else {
    for (int j = tid; j < H2; j += 256) x_bf[b * KX + E_DIM + j] = 0;
    const float* er = encoded + ((size_t)b * SEQ + 1) * H2;
    for (int j = tid; j < H_DIM; j += 256) {
      float acc = Ws_b[j];
      const float* wr = Ws_W + (size_t)j * H2;
      for (int k = 0; k < H2; ++k) acc = fmaf(er[k], wr[k], acc);
      h0[b * H_DIM + j] = acc;
      h0_bf[b * H_DIM + j] = f2bf(acc);
    }
  }
}

// ---------------- gates GEMM (small)
__device__ __forceinline__ void gemm_small(const ushort* __restrict__ Abf,
                                           const float* __restrict__ W,
                                           const float* __restrict__ bias,
                                           float* __restrict__ out, int N, int kdim,
                                           int bid) {
  int tid = threadIdx.x;
  int lane = tid & 63, wv = tid >> 6;
  int l15 = lane & 15, lg = lane >> 4;
  int n0 = (bid * 4 + wv) * 16;
  int col = n0 + l15;
  bool valid = col < N;
  int colc = valid ? col : N - 1;
  f32x4 acc[4];
#pragma unroll
  for (int mt = 0; mt < 4; ++mt) acc[mt] = (f32x4){0.f, 0.f, 0.f, 0.f};
  const float* wrow = W + (size_t)colc * kdim + lg * 8;
  const ushort* arow = Abf + (size_t)l15 * kdim + lg * 8;
#pragma unroll 4
  for (int k0 = 0; k0 < kdim; k0 += 32) {
    float4 w0 = *(const float4*)(wrow + k0);
    float4 w1 = *(const float4*)(wrow + k0 + 4);
    bf16x8 bf = cvt8(w0, w1);
#pragma unroll
    for (int mt = 0; mt < 4; ++mt) {
      bf16x8 af = *(const bf16x8*)(arow + (size_t)mt * 16 * kdim + k0);
      acc[mt] = __builtin_amdgcn_mfma_f32_16x16x32_bf16(af, bf, acc[mt], 0, 0, 0);
    }
  }
  float bv = bias[colc];
  if (valid) {
#pragma unroll
    for (int mt = 0; mt < 4; ++mt)
#pragma unroll
      for (int r = 0; r < 4; ++r)
        out[(size_t)(mt * 16 + lg * 4 + r) * N + col] = acc[mt][r] + bv;
  }
}

__global__ __launch_bounds__(256) void mfma_gates(const ushort* __restrict__ x_bf,
                                                  const float* __restrict__ Wih,
                                                  const float* __restrict__ bih,
                                                  const ushort* __restrict__ h0_bf,
                                                  const float* __restrict__ Whh,
                                                  const float* __restrict__ bhh,
                                                  float* __restrict__ gi, float* __restrict__ gh) {
  if (blockIdx.y == 0)
    gemm_small(x_bf, Wih, bih, gi, G3, KX, blockIdx.x);
  else
    gemm_small(h0_bf, Whh, bhh, gh, G3, H_DIM, blockIdx.x);
}

// ---------------- K2: GRU cell -> state f32 (d_out) + bf16 (ws)
__global__ void k2_gru(const float* __restrict__ gi, const float* __restrict__ gh,
                       const float* __restrict__ h0, float* __restrict__ state_out,
                       ushort* __restrict__ state_bf) {
  int b = blockIdx.x, j = threadIdx.x;  // block = 512
  float ir = gi[b * G3 + j], iz = gi[b * G3 + H_DIM + j], inn = gi[b * G3 + 2 * H_DIM + j];
  float hr = gh[b * G3 + j], hz = gh[b * G3 + H_DIM + j], hn = gh[b * G3 + 2 * H_DIM + j];
  float r = sigmf(ir + hr);
  float z = sigmf(iz + hz);
  float n = tanhf(inn + r * hn);
  float st = (1.f - z) * n + z * h0[b * H_DIM + j];
  state_out[b * H_DIM + j] = st;
  state_bf[b * H_DIM + j] = f2bf(st);
}

// ---------------- wo_m97: score_g = state @ Wo^T + b, + softmax partials.
// Exact k4_mfma9 structure: grid 782 (64-col tile = contiguous 128KB of Wo per
// block), 4 waves, BK=64, 8 iters, dbuf LDS [A 8KB | W 16KB]x2, one barrier/iter.
// Wave wv stages A rows wv*16..+15 (bf16, from L2-resident state_bf) and its own
// 16 W cols (f32); consumes all 4 A m-frags x its W n-frag (8 MFMA/iter).
__global__ __launch_bounds__(256) void wo_m97(const ushort* __restrict__ state_bf,
                                              const float* __restrict__ Wo_W,
                                              const float* __restrict__ Wo_b,
                                              float* __restrict__ out,
                                              float* __restrict__ redg) {
  __shared__ char lds[2][24576];  // [buf][ A 8KB (slot mf*2+ks) | W 16KB (wv*4 + ks*2+half) ]
  __shared__ float sm[4][64], ss[4][64];
  int tid = threadIdx.x, lane = tid & 63, wv = tid >> 6;
  int l15 = lane & 15, lg = lane >> 4;
  int bid = blockIdx.x;
  int n0 = bid * 64;
  int colw = n0 + wv * 16 + l15;
  bool vok = colw < V;
  int ccw = vok ? colw : V - 1;
  const ushort* asrc = state_bf + (size_t)(wv * 16 + l15) * H_DIM + lg * 8;
  const float* wsrc = Wo_W + (size_t)ccw * H_DIM + lg * 8;

  f32x4 acc[4];
#pragma unroll
  for (int mf = 0; mf < 4; ++mf) acc[mf] = (f32x4){0.f, 0.f, 0.f, 0.f};

#define STG(buf, it) do {                                               \
    char* d_ = &lds[buf][0];                                            \
    gload16(asrc + (it) * 64,      d_ + (wv * 2 + 0) * 1024);           \
    gload16(asrc + (it) * 64 + 32, d_ + (wv * 2 + 1) * 1024);           \
    gload16(wsrc + (it) * 64,      d_ + 8192 + (wv * 4 + 0) * 1024);    \
    gload16(wsrc + (it) * 64 + 4,  d_ + 8192 + (wv * 4 + 1) * 1024);    \
    gload16(wsrc + (it) * 64 + 32, d_ + 8192 + (wv * 4 + 2) * 1024);    \
    gload16(wsrc + (it) * 64 + 36, d_ + 8192 + (wv * 4 + 3) * 1024);    \
  } while (0)

  STG(0, 0);
  __syncthreads();
#pragma unroll 1
  for (int it = 0; it < 8; ++it) {
    int cur = it & 1;
    if (it < 7) STG(cur ^ 1, it + 1);
    const char* base = &lds[cur][0];
#pragma unroll
    for (int ks = 0; ks < 2; ++ks) {
      float4 w0 = *(const float4*)(base + 8192 + (wv * 4 + ks * 2 + 0) * 1024 + lane * 16);
      float4 w1 = *(const float4*)(base + 8192 + (wv * 4 + ks * 2 + 1) * 1024 + lane * 16);
      bf16x8 wf = cvt8(w0, w1);
#pragma unroll
      for (int mf = 0; mf < 4; ++mf) {
        bf16x8 a = *(const bf16x8*)(base + (mf * 2 + ks) * 1024 + lane * 16);
        acc[mf] = __builtin_amdgcn_mfma_f32_16x16x32_bf16(a, wf, acc[mf], 0, 0, 0);
      }
    }
    __syncthreads();  // next buffer staged & visible, cur reads done
  }
#undef STG

  float bv = Wo_b[ccw];
#pragma unroll
  for (int mf = 0; mf < 4; ++mf)
#pragma unroll
    for (int r = 0; r < 4; ++r) {
      size_t row = (size_t)(mf * 16 + lg * 4 + r) * V;
      if (vok) out[row + colw] = acc[mf][r] + bv;
    }
  // per-block online (max,sumexp) partials over this block's 64 cols
#pragma unroll
  for (int mf = 0; mf < 4; ++mf)
#pragma unroll
    for (int r = 0; r < 4; ++r) {
      float a0 = vok ? acc[mf][r] + bv : -1e30f;
      float mx = a0;
#pragma unroll
      for (int off = 1; off < 16; off <<= 1) mx = fmaxf(mx, __shfl_xor(mx, off, 64));
      float e = vok ? __expf(a0 - mx) : 0.f;
#pragma unroll
      for (int off = 1; off < 16; off <<= 1) e += __shfl_xor(e, off, 64);
      if (l15 == 0) {
        sm[wv][mf * 16 + lg * 4 + r] = mx;
        ss[wv][mf * 16 + lg * 4 + r] = e;
      }
    }
  __syncthreads();
  if (tid < 64) {
    float M = -1e30f, S = 0.f;
#pragma unroll
    for (int w = 0; w < 4; ++w) {
      float m2 = sm[w][tid], s2 = ss[w][tid];
      float mn = fmaxf(M, m2);
      S = S * __expf(M - mn) + s2 * __expf(m2 - mn);
      M = mn;
    }
    redg[((size_t)tid * NBLK_WO + bid) * 2] = M;
    redg[((size_t)tid * NBLK_WO + bid) * 2 + 1] = S;
  }
}

// ---------------- K4 v9 (unchanged): m97-style block GEMM.
__global__ __launch_bounds__(256) void k4_mfma9(const ushort* __restrict__ enc_bf,
                                                const ushort* __restrict__ Wc_bf,
                                                const float* __restrict__ Wc_b,
                                                const float* __restrict__ state,
                                                float* __restrict__ scpart) {
  __shared__ char lds[2][24576];  // [buf][ A 8KB | B 16KB ]
  __shared__ float sred[4][64];
  int tid = threadIdx.x, lane = tid & 63, wv = tid >> 6;
  int l15 = lane & 15, lg = lane >> 4;
  int bid = blockIdx.x;
  int mtile = bid >> 2, ntile = bid & 3;
  int m0 = mtile * 64, n0 = ntile * 128;

  const ushort* asrc = enc_bf + (size_t)(m0 + wv * 16 + l15) * H2 + lg * 8;
  const ushort* bsrc0 = Wc_bf + (size_t)(n0 + (wv * 2 + 0) * 16 + l15) * H2 + lg * 8;
  const ushort* bsrc1 = Wc_bf + (size_t)(n0 + (wv * 2 + 1) * 16 + l15) * H2 + lg * 8;

  f32x4 acc[4][2];
#pragma unroll
  for (int mf = 0; mf < 4; ++mf)
#pragma unroll
    for (int nf = 0; nf < 2; ++nf) acc[mf][nf] = (f32x4){0.f, 0.f, 0.f, 0.f};

#define STG(buf, it) do {                                              \
    char* d_ = &lds[buf][0];                                           \
    gload16(asrc + (it) * 64,       d_ + (wv * 2 + 0) * 1024);         \
    gload16(asrc + (it) * 64 + 32,  d_ + (wv * 2 + 1) * 1024);         \
    gload16(bsrc0 + (it) * 64,      d_ + 8192 + (wv * 4 + 0) * 1024);  \
    gload16(bsrc0 + (it) * 64 + 32, d_ + 8192 + (wv * 4 + 1) * 1024);  \
    gload16(bsrc1 + (it) * 64,      d_ + 8192 + (wv * 4 + 2) * 1024);  \
    gload16(bsrc1 + (it) * 64 + 32, d_ + 8192 + (wv * 4 + 3) * 1024);  \
  } while (0)

  STG(0, 0);
  __syncthreads();
#pragma unroll 1
  for (int it = 0; it < 16; ++it) {
    int cur = it & 1;
    if (it < 15) STG(cur ^ 1, it + 1);
    const char* base = &lds[cur][0];
#pragma unroll
    for (int ks = 0; ks < 2; ++ks) {
      bf16x8 b0 = *(const bf16x8*)(base + 8192 + (wv * 4 + ks) * 1024 + lane * 16);
      bf16x8 b1 = *(const bf16x8*)(base + 8192 + (wv * 4 + 2 + ks) * 1024 + lane * 16);
#pragma unroll
      for (int mf = 0; mf < 4; ++mf) {
        bf16x8 a = *(const bf16x8*)(base + (mf * 2 + ks) * 1024 + lane * 16);
        acc[mf][0] = __builtin_amdgcn_mfma_f32_16x16x32_bf16(a, b0, acc[mf][0], 0, 0, 0);
        acc[mf][1] = __builtin_amdgcn_mfma_f32_16x16x32_bf16(a, b1, acc[mf][1], 0, 0, 0);
      }
    }
    __syncthreads();
  }
#undef STG

  float pv[4][4];
#pragma unroll
  for (int mf = 0; mf < 4; ++mf)
#pragma unroll
    for (int r = 0; r < 4; ++r) pv[mf][r] = 0.f;
#pragma unroll
  for (int nfl = 0; nfl < 2; ++nfl) {
    int n = n0 + (wv * 2 + nfl) * 16 + l15;
    float bias = Wc_b[n];
#pragma unroll
    for (int mf = 0; mf < 4; ++mf) {
      int mrow = m0 + mf * 16 + lg * 4;
#pragma unroll
      for (int r = 0; r < 4; ++r) {
        int b = (mrow + r) / SEQ;
        pv[mf][r] += tanhfast(acc[mf][nfl][r] + bias) * state[b * H_DIM + n];
      }
    }
  }
#pragma unroll
  for (int off = 1; off < 16; off <<= 1)
#pragma unroll
    for (int mf = 0; mf < 4; ++mf)
#pragma unroll
      for (int r = 0; r < 4; ++r) pv[mf][r] += __shfl_xor(pv[mf][r], off, 64);
  if (l15 == 0) {
#pragma unroll
    for (int mf = 0; mf < 4; ++mf)
#pragma unroll
      for (int r = 0; r < 4; ++r) sred[wv][mf * 16 + lg * 4 + r] = pv[mf][r];
  }
  __syncthreads();
  if (tid < 64) {
    float s = sred[0][tid] + sred[1][tid] + sred[2][tid] + sred[3][tid];
    scpart[(size_t)ntile * MROWS + m0 + tid] = s;
  }
}

// ---------------- kred: combine redg partials + score_c tail -> red[b] = (max, sum)
__global__ void kred(const float* __restrict__ redg, const float* __restrict__ scpart,
                     const int* __restrict__ eidx, float* __restrict__ red) {
  int b = blockIdx.x, tid = threadIdx.x;
  float m = -1e30f, s = 0.f;
  for (int i = tid; i < NBLK_WO; i += 256) {
    float m2 = redg[((size_t)b * NBLK_WO + i) * 2];
    float s2 = redg[((size_t)b * NBLK_WO + i) * 2 + 1];
    float mn = fmaxf(m, m2);
    s = s * __expf(m - mn) + s2 * __expf(m2 - mn);
    m = mn;
  }
  for (int i = tid; i < SEQ; i += 256) {
    int idx = b * SEQ + i;
    int ei = eidx[idx];
    float scv = scpart[idx] + scpart[MROWS + idx] + scpart[2 * MROWS + idx] +
                scpart[3 * MROWS + idx];
    float sc = tanhf(scv + (ei == 0 ? -1000.f : 0.f));
    float mn = fmaxf(m, sc);
    s = s * __expf(m - mn) + __expf(sc - mn);
    m = mn;
  }
  __shared__ float ms[256], ssh[256];
  ms[tid] = m; ssh[tid] = s;
  __syncthreads();
  for (int off = 128; off > 0; off >>= 1) {
    if (tid < off) {
      float m2 = ms[tid + off], s2 = ssh[tid + off];
      float mn = fmaxf(ms[tid], m2);
      ssh[tid] = ssh[tid] * __expf(ms[tid] - mn) + s2 * __expf(m2 - mn);
      ms[tid] = mn;
    }
    __syncthreads();
  }
  if (tid == 0) {
    red[b * 2] = ms[0];
    red[b * 2 + 1] = ssh[0];
  }
}

// ---------------- K7: score_g -> prob_g in place
__global__ void k7_probs(float* __restrict__ sg, const float* __restrict__ red) {
  int i = blockIdx.x * 256 + threadIdx.x;
  int b = i / 12500;
  float mm = red[b * 2], rd = 1.f / red[b * 2 + 1];
  float4* p = (float4*)sg;
  float4 v = p[i];
  v.x = __expf(v.x - mm) * rd;
  v.y = __expf(v.y - mm) * rd;
  v.z = __expf(v.z - mm) * rd;
  v.w = __expf(v.w - mm) * rd;
  p[i] = v;
}

// ---------------- K8: prob_c scatter-add + match-attn weighted sum
__global__ void k8_copy(const float* __restrict__ scpart, const int* __restrict__ eidx,
                        const int* __restrict__ input_idx, const float* __restrict__ red,
                        const float* __restrict__ encoded, float* __restrict__ out,
                        float* __restrict__ wout) {
  int b = blockIdx.x, tid = threadIdx.x;
  __shared__ float att_s[SEQ];
  __shared__ int cnt_s[256];
  float mm = red[b * 2], rd = 1.f / red[b * 2 + 1];
  int inp = input_idx[b];
  int cnt = 0;
  for (int s = tid; s < SEQ; s += 256) {
    int idx = b * SEQ + s;
    int ei = eidx[idx];
    float scv = scpart[idx] + scpart[MROWS + idx] + scpart[2 * MROWS + idx] +
                scpart[3 * MROWS + idx];
    float sc = tanhf(scv + (ei == 0 ? -1000.f : 0.f));
    float p = __expf(sc - mm) * rd;
    bool mt = (ei == inp);
    att_s[s] = mt ? p : 0.f;
    cnt += mt ? 1 : 0;
    atomicAdd(&out[(size_t)b * V + ei], p);
  }
  cnt_s[tid] = cnt;
  __syncthreads();
  for (int off = 128; off > 0; off >>= 1) {
    if (tid < off) cnt_s[tid] += cnt_s[tid + off];
    __syncthreads();
  }
  int c = cnt_s[0];
  float scale = (c > 1) ? 1.f / (float)c : 1.f;
  float w0 = 0, w1 = 0, w2 = 0, w3 = 0;
  for (int s = 0; s < SEQ; ++s) {
    float a = att_s[s];
    if (a != 0.f) {
      const float* er = encoded + ((size_t)b * SEQ + s) * H2;
      w0 += a * er[tid];
      w1 += a * er[tid + 256];
      w2 += a * er[tid + 512];
      w3 += a * er[tid + 768];
    }
  }
  wout[b * H2 + tid] = w0 * scale;
  wout[b * H2 + tid + 256] = w1 * scale;
  wout[b * H2 + tid + 512] = w2 * scale;
  wout[b * H2 + tid + 768] = w3 * scale;
}

extern "C" void kernel_launch(void* const* d_in, const int* in_sizes, int n_in,
                              void* d_out, int out_size, void* d_ws, size_t ws_size,
                              hipStream_t stream) {
  const int* input_idx = (const int*)d_in[0];
  const float* encoded = (const float*)d_in[1];
  const int* encoded_idx = (const int*)d_in[2];
  const float* prev_state = (const float*)d_in[3];
  const float* weighted = (const float*)d_in[4];
  const int* order_p = (const int*)d_in[5];
  const float* embed_W = (const float*)d_in[6];
  const float* Wih = (const float*)d_in[7];
  const float* Whh = (const float*)d_in[8];
  const float* bih = (const float*)d_in[9];
  const float* bhh = (const float*)d_in[10];
  const float* Ws_W = (const float*)d_in[11];
  const float* Ws_b = (const float*)d_in[12];
  const float* Wo_W = (const float*)d_in[13];
  const float* Wo_b = (const float*)d_in[14];
  const float* Wc_W = (const float*)d_in[15];
  const float* Wc_b = (const float*)d_in[16];

  float* ws = (float*)d_ws;
  float* out = (float*)d_out;
  ushort* x_bf = (ushort*)(ws + XBF_OFF);
  float* h0 = ws + H0_OFF;
  ushort* h0_bf = (ushort*)(ws + H0BF_OFF);
  float* gi = ws + GI_OFF;
  float* gh = ws + GH_OFF;
  ushort* state_bf = (ushort*)(ws + STBF_OFF);
  ushort* Wc_bf = (ushort*)(ws + WCBF_OFF);
  float* scpart = ws + SC_OFF;
  float* redg = ws + REDG_OFF;
  float* red = ws + RED_OFF;
  ushort* enc_bf = (ushort*)(ws + ENCBF_OFF);
  float* state = out + OUT_STATE;
  float* wout = out + OUT_W;

  kprep<<<3776, 256, 0, stream>>>(Wc_W, Wc_bf, encoded, enc_bf, input_idx, prev_state,
                                  weighted, order_p, embed_W, Ws_W, Ws_b, x_bf, h0, h0_bf);
  mfma_gates<<<dim3(24, 2), 256, 0, stream>>>(x_bf, Wih, bih, h0_bf, Whh, bhh, gi, gh);
  k2_gru<<<64, 512, 0, stream>>>(gi, gh, h0, state, state_bf);
  wo_m97<<<NBLK_WO, 256, 0, stream>>>(state_bf, Wo_W, Wo_b, out, redg);
  k4_mfma9<<<800, 256, 0, stream>>>(enc_bf, Wc_bf, Wc_b, state, scpart);
  kred<<<64, 256, 0, stream>>>(redg, scpart, encoded_idx, red);
  k7_probs<<<3125, 256, 0, stream>>>(out, red);
  k8_copy<<<64, 256, 0, stream>>>(scpart, encoded_idx, input_idx, red, encoded, out, wout);
}

// Round 14
// 160.244 us; speedup vs baseline: 1.0247x; 1.0247x over previous
//
#include <hip/hip_runtime.h>

#define V 50000
#define E_DIM 256
#define H_DIM 512
#define H2 1024
#define G3 1536
#define BSZ 64
#define SEQ 200
#define KX 1280
#define MROWS 12800
#define NBLK_WO 782  // ceil(50000/64)

// ws offsets (float units)
#define XBF_OFF   0        // 64*1280 bf16
#define H0_OFF    40960    // 64*512 f32
#define H0BF_OFF  73728    // 64*512 bf16
#define GI_OFF    90112    // 64*1536 f32
#define GH_OFF    188416   // 64*1536 f32
#define STBF_OFF  286720   // 64*512 bf16
#define WCBF_OFF  303104   // 512*1024 bf16
#define SC_OFF    565248   // 4*12800 f32 (n-tile partials)
#define REDG_OFF  616448   // 64*782*2 f32
#define RED_OFF   716544   // 64*2 f32
#define ENCBF_OFF 716672   // 12800*1024 bf16 = 3276800 f

// d_out layout (floats)
#define OUT_STATE 3200000
#define OUT_W     3232768

typedef __attribute__((ext_vector_type(8))) short bf16x8;
typedef __attribute__((ext_vector_type(4))) float f32x4;

__device__ __forceinline__ float sigmf(float x) { return 1.f / (1.f + __expf(-x)); }

__device__ __forceinline__ ushort f2bf(float f) {
  uint u = __float_as_uint(f);
  uint r = (u + 0x7FFFu + ((u >> 16) & 1u)) >> 16;
  return (ushort)r;
}

__device__ __forceinline__ float tanhfast(float x) {
  float xc = fminf(15.f, fmaxf(-15.f, x));
  float e = __expf(2.f * xc);
  return (e - 1.f) * __builtin_amdgcn_rcpf(e + 1.f);
}

// packed f32->bf16 (RNE)
__device__ __forceinline__ bf16x8 cvt8(float4 a, float4 b) {
  union { bf16x8 v; uint u[4]; } r;
  asm("v_cvt_pk_bf16_f32 %0, %1, %2" : "=v"(r.u[0]) : "v"(a.x), "v"(a.y));
  asm("v_cvt_pk_bf16_f32 %0, %1, %2" : "=v"(r.u[1]) : "v"(a.z), "v"(a.w));
  asm("v_cvt_pk_bf16_f32 %0, %1, %2" : "=v"(r.u[2]) : "v"(b.x), "v"(b.y));
  asm("v_cvt_pk_bf16_f32 %0, %1, %2" : "=v"(r.u[3]) : "v"(b.z), "v"(b.w));
  return r.v;
}

// async global->LDS, 16B per lane; lds base wave-uniform, HW adds lane*16.
__device__ __forceinline__ void gload16(const void* g, void* l) {
  __builtin_amdgcn_global_load_lds(
      (__attribute__((address_space(1))) void*)(g),
      (__attribute__((address_space(3))) void*)(l), 16, 0, 0);
}

// ---------------- kprep: Wc f32->bf16 (0..511) | encoded f32->bf16 (512..3711) |
//                  x_bf/h0 build (3712..3775)
__global__ void kprep(const float* __restrict__ Wc_W, ushort* __restrict__ Wc_bf,
                      const float* __restrict__ encoded, ushort* __restrict__ enc_bf,
                      const int* __restrict__ input_idx,
                      const float* __restrict__ prev_state, const float* __restrict__ weighted,
                      const int* __restrict__ order_p, const float* __restrict__ embed_W,
                      const float* __restrict__ Ws_W, const float* __restrict__ Ws_b,
                      ushort* __restrict__ x_bf, float* __restrict__ h0,
                      ushort* __restrict__ h0_bf) {
  int bid = blockIdx.x, tid = threadIdx.x;
  if (bid < 512) {
    int i = bid * 256 + tid;
    float4 v = ((const float4*)Wc_W)[i];
    ushort4 o;
    o.x = f2bf(v.x); o.y = f2bf(v.y); o.z = f2bf(v.z); o.w = f2bf(v.w);
    ((ushort4*)Wc_bf)[i] = o;
    return;
  }
  if (bid < 3712) {
    int base = (bid - 512) * 1024;
#pragma unroll
    for (int j = 0; j < 4; ++j) {
      int i = base + j * 256 + tid;
      float4 v = ((const float4*)encoded)[i];
      ushort4 o;
      o.x = f2bf(v.x); o.y = f2bf(v.y); o.z = f2bf(v.z); o.w = f2bf(v.w);
      ((ushort4*)enc_bf)[i] = o;
    }
    return;
  }
  int b = bid - 3712;
  int order = order_p[0];
  int idx = input_idx[b];
  x_bf[b * KX + tid] = f2bf(embed_W[(size_t)idx * E_DIM + tid]);
  if (order != 0) {
    for (int j = tid; j < H2; j += 256) x_bf[b * KX + E_DIM + j] = f2bf(weighted[b * H2 + j]);
    for (int j = tid; j < H_DIM; j += 256) {
      float v = prev_state[b * H_DIM + j];
      h0[b * H_DIM + j] = v;
      h0_bf[b * H_DIM + j] = f2bf(v);
    }
  } else {
    for (int j = tid; j < H2; j += 256) x_bf[b * KX + E_DIM + j] = 0;
    const float* er = encoded + ((size_t)b * SEQ + 1) * H2;
    for (int j = tid; j < H_DIM; j += 256) {
      float acc = Ws_b[j];
      const float* wr = Ws_W + (size_t)j * H2;
      for (int k = 0; k < H2; ++k) acc = fmaf(er[k], wr[k], acc);
      h0[b * H_DIM + j] = acc;
      h0_bf[b * H_DIM + j] = f2bf(acc);
    }
  }
}

// ---------------- gates GEMM (small)
__device__ __forceinline__ void gemm_small(const ushort* __restrict__ Abf,
                                           const float* __restrict__ W,
                                           const float* __restrict__ bias,
                                           float* __restrict__ out, int N, int kdim,
                                           int bid) {
  int tid = threadIdx.x;
  int lane = tid & 63, wv = tid >> 6;
  int l15 = lane & 15, lg = lane >> 4;
  int n0 = (bid * 4 + wv) * 16;
  int col = n0 + l15;
  bool valid = col < N;
  int colc = valid ? col : N - 1;
  f32x4 acc[4];
#pragma unroll
  for (int mt = 0; mt < 4; ++mt) acc[mt] = (f32x4){0.f, 0.f, 0.f, 0.f};
  const float* wrow = W + (size_t)colc * kdim + lg * 8;
  const ushort* arow = Abf + (size_t)l15 * kdim + lg * 8;
#pragma unroll 4
  for (int k0 = 0; k0 < kdim; k0 += 32) {
    float4 w0 = *(const float4*)(wrow + k0);
    float4 w1 = *(const float4*)(wrow + k0 + 4);
    bf16x8 bf = cvt8(w0, w1);
#pragma unroll
    for (int mt = 0; mt < 4; ++mt) {
      bf16x8 af = *(const bf16x8*)(arow + (size_t)mt * 16 * kdim + k0);
      acc[mt] = __builtin_amdgcn_mfma_f32_16x16x32_bf16(af, bf, acc[mt], 0, 0, 0);
    }
  }
  float bv = bias[colc];
  if (valid) {
#pragma unroll
    for (int mt = 0; mt < 4; ++mt)
#pragma unroll
      for (int r = 0; r < 4; ++r)
        out[(size_t)(mt * 16 + lg * 4 + r) * N + col] = acc[mt][r] + bv;
  }
}

__global__ __launch_bounds__(256) void mfma_gates(const ushort* __restrict__ x_bf,
                                                  const float* __restrict__ Wih,
                                                  const float* __restrict__ bih,
                                                  const ushort* __restrict__ h0_bf,
                                                  const float* __restrict__ Whh,
                                                  const float* __restrict__ bhh,
                                                  float* __restrict__ gi, float* __restrict__ gh) {
  if (blockIdx.y == 0)
    gemm_small(x_bf, Wih, bih, gi, G3, KX, blockIdx.x);
  else
    gemm_small(h0_bf, Whh, bhh, gh, G3, H_DIM, blockIdx.x);
}

// ---------------- K2: GRU cell -> state f32 (d_out) + bf16 (ws)
__global__ void k2_gru(const float* __restrict__ gi, const float* __restrict__ gh,
                       const float* __restrict__ h0, float* __restrict__ state_out,
                       ushort* __restrict__ state_bf) {
  int b = blockIdx.x, j = threadIdx.x;  // block = 512
  float ir = gi[b * G3 + j], iz = gi[b * G3 + H_DIM + j], inn = gi[b * G3 + 2 * H_DIM + j];
  float hr = gh[b * G3 + j], hz = gh[b * G3 + H_DIM + j], hn = gh[b * G3 + 2 * H_DIM + j];
  float r = sigmf(ir + hr);
  float z = sigmf(iz + hz);
  float n = tanhf(inn + r * hn);
  float st = (1.f - z) * n + z * h0[b * H_DIM + j];
  state_out[b * H_DIM + j] = st;
  state_bf[b * H_DIM + j] = f2bf(st);
}

// ---------------- fused big kernel: interleaved wo (score_g) + k4 (score_c) blocks.
// Both paths are the verified round-13 m97-structure bodies. bid even -> k4 task
// bid/2 (800); bid odd -> wo task bid/2 (<782, else early return). Interleaving puts
// a mix of both latency-bound block types on every CU so their stalls overlap.
__global__ __launch_bounds__(256) void fused_big(const ushort* __restrict__ enc_bf,
                                                 const ushort* __restrict__ Wc_bf,
                                                 const float* __restrict__ Wc_b,
                                                 const float* __restrict__ state,
                                                 const ushort* __restrict__ state_bf,
                                                 const float* __restrict__ Wo_W,
                                                 const float* __restrict__ Wo_b,
                                                 float* __restrict__ out,
                                                 float* __restrict__ redg,
                                                 float* __restrict__ scpart) {
  __shared__ char lds[2][24576];
  __shared__ float s0buf[4][64], s1buf[4][64];
  int tid = threadIdx.x, lane = tid & 63, wv = tid >> 6;
  int l15 = lane & 15, lg = lane >> 4;
  int bid = blockIdx.x;

  if (bid & 1) {
    // ================= wo path: score_g tile (64 cols x 64 rows) =================
    int wt = bid >> 1;
    if (wt >= NBLK_WO) return;
    int n0 = wt * 64;
    int colw = n0 + wv * 16 + l15;
    bool vok = colw < V;
    int ccw = vok ? colw : V - 1;
    const ushort* asrc = state_bf + (size_t)(wv * 16 + l15) * H_DIM + lg * 8;
    const float* wsrc = Wo_W + (size_t)ccw * H_DIM + lg * 8;

    f32x4 acc[4];
#pragma unroll
    for (int mf = 0; mf < 4; ++mf) acc[mf] = (f32x4){0.f, 0.f, 0.f, 0.f};

#define STGW(buf, it) do {                                               \
    char* d_ = &lds[buf][0];                                             \
    gload16(asrc + (it) * 64,      d_ + (wv * 2 + 0) * 1024);            \
    gload16(asrc + (it) * 64 + 32, d_ + (wv * 2 + 1) * 1024);            \
    gload16(wsrc + (it) * 64,      d_ + 8192 + (wv * 4 + 0) * 1024);     \
    gload16(wsrc + (it) * 64 + 4,  d_ + 8192 + (wv * 4 + 1) * 1024);     \
    gload16(wsrc + (it) * 64 + 32, d_ + 8192 + (wv * 4 + 2) * 1024);     \
    gload16(wsrc + (it) * 64 + 36, d_ + 8192 + (wv * 4 + 3) * 1024);     \
  } while (0)

    STGW(0, 0);
    __syncthreads();
#pragma unroll 1
    for (int it = 0; it < 8; ++it) {
      int cur = it & 1;
      if (it < 7) STGW(cur ^ 1, it + 1);
      const char* base = &lds[cur][0];
#pragma unroll
      for (int ks = 0; ks < 2; ++ks) {
        float4 w0 = *(const float4*)(base + 8192 + (wv * 4 + ks * 2 + 0) * 1024 + lane * 16);
        float4 w1 = *(const float4*)(base + 8192 + (wv * 4 + ks * 2 + 1) * 1024 + lane * 16);
        bf16x8 wf = cvt8(w0, w1);
#pragma unroll
        for (int mf = 0; mf < 4; ++mf) {
          bf16x8 a = *(const bf16x8*)(base + (mf * 2 + ks) * 1024 + lane * 16);
          acc[mf] = __builtin_amdgcn_mfma_f32_16x16x32_bf16(a, wf, acc[mf], 0, 0, 0);
        }
      }
      __syncthreads();
    }
#undef STGW

    float bv = Wo_b[ccw];
#pragma unroll
    for (int mf = 0; mf < 4; ++mf)
#pragma unroll
      for (int r = 0; r < 4; ++r) {
        size_t row = (size_t)(mf * 16 + lg * 4 + r) * V;
        if (vok) out[row + colw] = acc[mf][r] + bv;
      }
#pragma unroll
    for (int mf = 0; mf < 4; ++mf)
#pragma unroll
      for (int r = 0; r < 4; ++r) {
        float a0 = vok ? acc[mf][r] + bv : -1e30f;
        float mx = a0;
#pragma unroll
        for (int off = 1; off < 16; off <<= 1) mx = fmaxf(mx, __shfl_xor(mx, off, 64));
        float e = vok ? __expf(a0 - mx) : 0.f;
#pragma unroll
        for (int off = 1; off < 16; off <<= 1) e += __shfl_xor(e, off, 64);
        if (l15 == 0) {
          s0buf[wv][mf * 16 + lg * 4 + r] = mx;
          s1buf[wv][mf * 16 + lg * 4 + r] = e;
        }
      }
    __syncthreads();
    if (tid < 64) {
      float M = -1e30f, S = 0.f;
#pragma unroll
      for (int w = 0; w < 4; ++w) {
        float m2 = s0buf[w][tid], s2 = s1buf[w][tid];
        float mn = fmaxf(M, m2);
        S = S * __expf(M - mn) + s2 * __expf(m2 - mn);
        M = mn;
      }
      redg[((size_t)tid * NBLK_WO + wt) * 2] = M;
      redg[((size_t)tid * NBLK_WO + wt) * 2 + 1] = S;
    }
  } else {
    // ================= k4 path: score_c partial tile (64 rows x 128 cols) ========
    int kt = bid >> 1;  // 0..799
    int mtile = kt >> 2, ntile = kt & 3;
    int m0 = mtile * 64, n0 = ntile * 128;

    const ushort* asrc = enc_bf + (size_t)(m0 + wv * 16 + l15) * H2 + lg * 8;
    const ushort* bsrc0 = Wc_bf + (size_t)(n0 + (wv * 2 + 0) * 16 + l15) * H2 + lg * 8;
    const ushort* bsrc1 = Wc_bf + (size_t)(n0 + (wv * 2 + 1) * 16 + l15) * H2 + lg * 8;

    f32x4 acc[4][2];
#pragma unroll
    for (int mf = 0; mf < 4; ++mf)
#pragma unroll
      for (int nf = 0; nf < 2; ++nf) acc[mf][nf] = (f32x4){0.f, 0.f, 0.f, 0.f};

#define STG(buf, it) do {                                              \
    char* d_ = &lds[buf][0];                                           \
    gload16(asrc + (it) * 64,       d_ + (wv * 2 + 0) * 1024);         \
    gload16(asrc + (it) * 64 + 32,  d_ + (wv * 2 + 1) * 1024);         \
    gload16(bsrc0 + (it) * 64,      d_ + 8192 + (wv * 4 + 0) * 1024);  \
    gload16(bsrc0 + (it) * 64 + 32, d_ + 8192 + (wv * 4 + 1) * 1024);  \
    gload16(bsrc1 + (it) * 64,      d_ + 8192 + (wv * 4 + 2) * 1024);  \
    gload16(bsrc1 + (it) * 64 + 32, d_ + 8192 + (wv * 4 + 3) * 1024);  \
  } while (0)

    STG(0, 0);
    __syncthreads();
#pragma unroll 1
    for (int it = 0; it < 16; ++it) {
      int cur = it & 1;
      if (it < 15) STG(cur ^ 1, it + 1);
      const char* base = &lds[cur][0];
#pragma unroll
      for (int ks = 0; ks < 2; ++ks) {
        bf16x8 b0 = *(const bf16x8*)(base + 8192 + (wv * 4 + ks) * 1024 + lane * 16);
        bf16x8 b1 = *(const bf16x8*)(base + 8192 + (wv * 4 + 2 + ks) * 1024 + lane * 16);
#pragma unroll
        for (int mf = 0; mf < 4; ++mf) {
          bf16x8 a = *(const bf16x8*)(base + (mf * 2 + ks) * 1024 + lane * 16);
          acc[mf][0] = __builtin_amdgcn_mfma_f32_16x16x32_bf16(a, b0, acc[mf][0], 0, 0, 0);
          acc[mf][1] = __builtin_amdgcn_mfma_f32_16x16x32_bf16(a, b1, acc[mf][1], 0, 0, 0);
        }
      }
      __syncthreads();
    }
#undef STG

    float pv[4][4];
#pragma unroll
    for (int mf = 0; mf < 4; ++mf)
#pragma unroll
      for (int r = 0; r < 4; ++r) pv[mf][r] = 0.f;
#pragma unroll
    for (int nfl = 0; nfl < 2; ++nfl) {
      int n = n0 + (wv * 2 + nfl) * 16 + l15;
      float bias = Wc_b[n];
#pragma unroll
      for (int mf = 0; mf < 4; ++mf) {
        int mrow = m0 + mf * 16 + lg * 4;
#pragma unroll
        for (int r = 0; r < 4; ++r) {
          int b = (mrow + r) / SEQ;
          pv[mf][r] += tanhfast(acc[mf][nfl][r] + bias) * state[b * H_DIM + n];
        }
      }
    }
#pragma unroll
    for (int off = 1; off < 16; off <<= 1)
#pragma unroll
      for (int mf = 0; mf < 4; ++mf)
#pragma unroll
        for (int r = 0; r < 4; ++r) pv[mf][r] += __shfl_xor(pv[mf][r], off, 64);
    if (l15 == 0) {
#pragma unroll
      for (int mf = 0; mf < 4; ++mf)
#pragma unroll
        for (int r = 0; r < 4; ++r) s0buf[wv][mf * 16 + lg * 4 + r] = pv[mf][r];
    }
    __syncthreads();
    if (tid < 64) {
      float s = s0buf[0][tid] + s0buf[1][tid] + s0buf[2][tid] + s0buf[3][tid];
      scpart[(size_t)ntile * MROWS + m0 + tid] = s;
    }
  }
}

// ---------------- kred: combine redg partials + score_c tail -> red[b] = (max, sum)
__global__ void kred(const float* __restrict__ redg, const float* __restrict__ scpart,
                     const int* __restrict__ eidx, float* __restrict__ red) {
  int b = blockIdx.x, tid = threadIdx.x;
  float m = -1e30f, s = 0.f;
  for (int i = tid; i < NBLK_WO; i += 256) {
    float m2 = redg[((size_t)b * NBLK_WO + i) * 2];
    float s2 = redg[((size_t)b * NBLK_WO + i) * 2 + 1];
    float mn = fmaxf(m, m2);
    s = s * __expf(m - mn) + s2 * __expf(m2 - mn);
    m = mn;
  }
  for (int i = tid; i < SEQ; i += 256) {
    int idx = b * SEQ + i;
    int ei = eidx[idx];
    float scv = scpart[idx] + scpart[MROWS + idx] + scpart[2 * MROWS + idx] +
                scpart[3 * MROWS + idx];
    float sc = tanhf(scv + (ei == 0 ? -1000.f : 0.f));
    float mn = fmaxf(m, sc);
    s = s * __expf(m - mn) + __expf(sc - mn);
    m = mn;
  }
  __shared__ float ms[256], ssh[256];
  ms[tid] = m; ssh[tid] = s;
  __syncthreads();
  for (int off = 128; off > 0; off >>= 1) {
    if (tid < off) {
      float m2 = ms[tid + off], s2 = ssh[tid + off];
      float mn = fmaxf(ms[tid], m2);
      ssh[tid] = ssh[tid] * __expf(ms[tid] - mn) + s2 * __expf(m2 - mn);
      ms[tid] = mn;
    }
    __syncthreads();
  }
  if (tid == 0) {
    red[b * 2] = ms[0];
    red[b * 2 + 1] = ssh[0];
  }
}

// ---------------- K7: score_g -> prob_g in place
__global__ void k7_probs(float* __restrict__ sg, const float* __restrict__ red) {
  int i = blockIdx.x * 256 + threadIdx.x;
  int b = i / 12500;
  float mm = red[b * 2], rd = 1.f / red[b * 2 + 1];
  float4* p = (float4*)sg;
  float4 v = p[i];
  v.x = __expf(v.x - mm) * rd;
  v.y = __expf(v.y - mm) * rd;
  v.z = __expf(v.z - mm) * rd;
  v.w = __expf(v.w - mm) * rd;
  p[i] = v;
}

// ---------------- K8: prob_c scatter-add + match-attn weighted sum
__global__ void k8_copy(const float* __restrict__ scpart, const int* __restrict__ eidx,
                        const int* __restrict__ input_idx, const float* __restrict__ red,
                        const float* __restrict__ encoded, float* __restrict__ out,
                        float* __restrict__ wout) {
  int b = blockIdx.x, tid = threadIdx.x;
  __shared__ float att_s[SEQ];
  __shared__ int cnt_s[256];
  float mm = red[b * 2], rd = 1.f / red[b * 2 + 1];
  int inp = input_idx[b];
  int cnt = 0;
  for (int s = tid; s < SEQ; s += 256) {
    int idx = b * SEQ + s;
    int ei = eidx[idx];
    float scv = scpart[idx] + scpart[MROWS + idx] + scpart[2 * MROWS + idx] +
                scpart[3 * MROWS + idx];
    float sc = tanhf(scv + (ei == 0 ? -1000.f : 0.f));
    float p = __expf(sc - mm) * rd;
    bool mt = (ei == inp);
    att_s[s] = mt ? p : 0.f;
    cnt += mt ? 1 : 0;
    atomicAdd(&out[(size_t)b * V + ei], p);
  }
  cnt_s[tid] = cnt;
  __syncthreads();
  for (int off = 128; off > 0; off >>= 1) {
    if (tid < off) cnt_s[tid] += cnt_s[tid + off];
    __syncthreads();
  }
  int c = cnt_s[0];
  float scale = (c > 1) ? 1.f / (float)c : 1.f;
  float w0 = 0, w1 = 0, w2 = 0, w3 = 0;
  for (int s = 0; s < SEQ; ++s) {
    float a = att_s[s];
    if (a != 0.f) {
      const float* er = encoded + ((size_t)b * SEQ + s) * H2;
      w0 += a * er[tid];
      w1 += a * er[tid + 256];
      w2 += a * er[tid + 512];
      w3 += a * er[tid + 768];
    }
  }
  wout[b * H2 + tid] = w0 * scale;
  wout[b * H2 + tid + 256] = w1 * scale;
  wout[b * H2 + tid + 512] = w2 * scale;
  wout[b * H2 + tid + 768] = w3 * scale;
}

extern "C" void kernel_launch(void* const* d_in, const int* in_sizes, int n_in,
                              void* d_out, int out_size, void* d_ws, size_t ws_size,
                              hipStream_t stream) {
  const int* input_idx = (const int*)d_in[0];
  const float* encoded = (const float*)d_in[1];
  const int* encoded_idx = (const int*)d_in[2];
  const float* prev_state = (const float*)d_in[3];
  const float* weighted = (const float*)d_in[4];
  const int* order_p = (const int*)d_in[5];
  const float* embed_W = (const float*)d_in[6];
  const float* Wih = (const float*)d_in[7];
  const float* Whh = (const float*)d_in[8];
  const float* bih = (const float*)d_in[9];
  const float* bhh = (const float*)d_in[10];
  const float* Ws_W = (const float*)d_in[11];
  const float* Ws_b = (const float*)d_in[12];
  const float* Wo_W = (const float*)d_in[13];
  const float* Wo_b = (const float*)d_in[14];
  const float* Wc_W = (const float*)d_in[15];
  const float* Wc_b = (const float*)d_in[16];

  float* ws = (float*)d_ws;
  float* out = (float*)d_out;
  ushort* x_bf = (ushort*)(ws + XBF_OFF);
  float* h0 = ws + H0_OFF;
  ushort* h0_bf = (ushort*)(ws + H0BF_OFF);
  float* gi = ws + GI_OFF;
  float* gh = ws + GH_OFF;
  ushort* state_bf = (ushort*)(ws + STBF_OFF);
  ushort* Wc_bf = (ushort*)(ws + WCBF_OFF);
  float* scpart = ws + SC_OFF;
  float* redg = ws + REDG_OFF;
  float* red = ws + RED_OFF;
  ushort* enc_bf = (ushort*)(ws + ENCBF_OFF);
  float* state = out + OUT_STATE;
  float* wout = out + OUT_W;

  kprep<<<3776, 256, 0, stream>>>(Wc_W, Wc_bf, encoded, enc_bf, input_idx, prev_state,
                                  weighted, order_p, embed_W, Ws_W, Ws_b, x_bf, h0, h0_bf);
  mfma_gates<<<dim3(24, 2), 256, 0, stream>>>(x_bf, Wih, bih, h0_bf, Whh, bhh, gi, gh);
  k2_gru<<<64, 512, 0, stream>>>(gi, gh, h0, state, state_bf);
  fused_big<<<1600, 256, 0, stream>>>(enc_bf, Wc_bf, Wc_b, state, state_bf,
                                      Wo_W, Wo_b, out, redg, scpart);
  kred<<<64, 256, 0, stream>>>(redg, scpart, encoded_idx, red);
  k7_probs<<<3125, 256, 0, stream>>>(out, red);
  k8_copy<<<64, 256, 0, stream>>>(scpart, encoded_idx, input_idx, red, encoded, out, wout);
}